// Round 2
// baseline (4487.444 us; speedup 1.0000x reference)
//
#include <hip/hip_runtime.h>
#include <math.h>

#define BB 4
#define NN 1024
#define DIMM 1024
#define HHH 16
#define DHH 64
#define BN 4096            // B*N rows
#define EPS_LN 1e-6f

// ============================================================
// Complex GEMM:  C = A @ B^T + bias   (A:[4096,1024], B:[1024,1024], NT)
// real = Ar@Br^T - Ai@Bi^T + br ; imag = Ar@Bi^T + Ai@Br^T + bi
// 64x64 tile, 256 threads, 4x4 register blocking.
// ============================================================
#define TS 64
#define KTILE 16

__global__ __launch_bounds__(256) void cgemm_nt(
    const float* __restrict__ Ar, const float* __restrict__ Ai,
    const float* __restrict__ Br, const float* __restrict__ Bi,
    const float* __restrict__ bias_r, const float* __restrict__ bias_i,
    float* __restrict__ Cr, float* __restrict__ Ci, int ldc)
{
  __shared__ float sAr[TS][KTILE + 1], sAi[TS][KTILE + 1];
  __shared__ float sBr[TS][KTILE + 1], sBi[TS][KTILE + 1];
  const int tid = threadIdx.x;
  const int tx = tid & 15, ty = tid >> 4;
  const int row0 = blockIdx.y * TS, col0 = blockIdx.x * TS;
  float accr[4][4] = {}, acci[4][4] = {};
  for (int k0 = 0; k0 < DIMM; k0 += KTILE) {
    for (int t = tid; t < TS * KTILE; t += 256) {
      int r = t >> 4, c = t & 15;
      sAr[r][c] = Ar[(size_t)(row0 + r) * DIMM + k0 + c];
      sAi[r][c] = Ai[(size_t)(row0 + r) * DIMM + k0 + c];
      sBr[r][c] = Br[(size_t)(col0 + r) * DIMM + k0 + c];
      sBi[r][c] = Bi[(size_t)(col0 + r) * DIMM + k0 + c];
    }
    __syncthreads();
#pragma unroll
    for (int kk = 0; kk < KTILE; ++kk) {
      float ar[4], ai[4], wr[4], wi[4];
#pragma unroll
      for (int i = 0; i < 4; ++i) { ar[i] = sAr[ty * 4 + i][kk]; ai[i] = sAi[ty * 4 + i][kk]; }
#pragma unroll
      for (int j = 0; j < 4; ++j) { wr[j] = sBr[tx * 4 + j][kk]; wi[j] = sBi[tx * 4 + j][kk]; }
#pragma unroll
      for (int i = 0; i < 4; ++i)
#pragma unroll
        for (int j = 0; j < 4; ++j) {
          accr[i][j] += ar[i] * wr[j] - ai[i] * wi[j];
          acci[i][j] += ar[i] * wi[j] + ai[i] * wr[j];
        }
    }
    __syncthreads();
  }
#pragma unroll
  for (int i = 0; i < 4; ++i) {
    int r = row0 + ty * 4 + i;
#pragma unroll
    for (int j = 0; j < 4; ++j) {
      int c = col0 + tx * 4 + j;
      Cr[(size_t)r * ldc + c] = accr[i][j] + bias_r[c];
      Ci[(size_t)r * ldc + c] = acci[i][j] + bias_i[c];
    }
  }
}

// ============================================================
// Complex LayerNorm over last dim (in-place): normalize |z|, keep phase.
// One block (256 thr) per row of 1024.
// ============================================================
__global__ __launch_bounds__(256) void cln_kernel(
    float* __restrict__ re, float* __restrict__ im,
    const float* __restrict__ gamma, const float* __restrict__ beta)
{
  __shared__ float red[8];
  const int row = blockIdx.x;
  const int tid = threadIdx.x;
  float* pr = re + (size_t)row * DIMM;
  float* pi = im + (size_t)row * DIMM;
  float vr[4], vi[4], mg[4];
  float s = 0.f, s2 = 0.f;
#pragma unroll
  for (int t = 0; t < 4; ++t) {
    int c = tid + t * 256;
    vr[t] = pr[c]; vi[t] = pi[c];
    mg[t] = sqrtf(vr[t] * vr[t] + vi[t] * vi[t]);
    s += mg[t]; s2 += mg[t] * mg[t];
  }
#pragma unroll
  for (int o = 32; o; o >>= 1) { s += __shfl_down(s, o); s2 += __shfl_down(s2, o); }
  if ((tid & 63) == 0) { red[tid >> 6] = s; red[4 + (tid >> 6)] = s2; }
  __syncthreads();
  if (tid == 0) {
    float S = red[0] + red[1] + red[2] + red[3];
    float S2 = red[4] + red[5] + red[6] + red[7];
    float mean = S * (1.f / DIMM);
    float var = S2 * (1.f / DIMM) - mean * mean;
    red[0] = mean;
    red[1] = rsqrtf(var + EPS_LN);
  }
  __syncthreads();
  float mean = red[0], inv = red[1];
#pragma unroll
  for (int t = 0; t < 4; ++t) {
    int c = tid + t * 256;
    float nm = (mg[t] - mean) * inv * gamma[c] + beta[c];
    float invm = mg[t] > 0.f ? 1.f / mg[t] : 0.f;
    float cr = mg[t] > 0.f ? vr[t] * invm : 1.f;
    float ci = mg[t] > 0.f ? vi[t] * invm : 0.f;
    pr[c] = nm * cr;
    pi[c] = nm * ci;
  }
}

// ============================================================
// 1024-point radix-2 DIF FFT along n, ortho norm (1/32 both directions).
// One block = 512 threads handles FD=4 d-lanes of one (b,h).
// Strides parametrize head-gather input and transposed/natural output.
// sign = -1 forward, +1 inverse. Bit-reversal folded into the store read.
// ============================================================
#define FD 4
__global__ __launch_bounds__(512) void fft_kernel(
    const float* __restrict__ inR, const float* __restrict__ inI,
    float* __restrict__ outR, float* __restrict__ outI,
    int in_sb, int in_sh, int in_sn, int in_sd,
    int out_sb, int out_sh, int out_sn, int out_sd,
    float sign)
{
  __shared__ float lr[FD][NN + 1], li[FD][NN + 1];
  const int tid = threadIdx.x;
  const int dc = blockIdx.x & 15;   // 16 d-chunks of 4
  const int bh = blockIdx.x >> 4;
  const int b = bh >> 4, h = bh & 15;
  const float* bR = inR + (size_t)b * in_sb + (size_t)h * in_sh;
  const float* bI = inI + (size_t)b * in_sb + (size_t)h * in_sh;
#pragma unroll
  for (int it = 0; it < 8; ++it) {
    int flat = it * 512 + tid;
    int ds = flat & 3, n = flat >> 2;
    size_t ga = (size_t)(dc * FD + ds) * in_sd + (size_t)n * in_sn;
    lr[ds][n] = bR[ga];
    li[ds][n] = bI[ga];
  }
  __syncthreads();
  const int dsub = tid & 3;
  const int jb = tid >> 2;          // 0..127
  for (int hs = 9; hs >= 0; --hs) {
    int half = 1 << hs;
    float angstep = sign * 3.14159265358979323846f / (float)half;
#pragma unroll
    for (int it = 0; it < 4; ++it) {
      int j = jb + it * 128;        // 0..511
      int o = j & (half - 1);
      int i0 = ((j >> hs) << (hs + 1)) + o;
      int i1 = i0 + half;
      float ar = lr[dsub][i0], ai = li[dsub][i0];
      float br_ = lr[dsub][i1], bi_ = li[dsub][i1];
      lr[dsub][i0] = ar + br_;
      li[dsub][i0] = ai + bi_;
      float sr = ar - br_, si = ai - bi_;
      float sn, cs;
      __sincosf(angstep * (float)o, &sn, &cs);
      lr[dsub][i1] = sr * cs - si * sn;
      li[dsub][i1] = sr * sn + si * cs;
    }
    __syncthreads();
  }
  float* oR = outR + (size_t)b * out_sb + (size_t)h * out_sh;
  float* oI = outI + (size_t)b * out_sb + (size_t)h * out_sh;
#pragma unroll
  for (int it = 0; it < 8; ++it) {
    int flat = it * 512 + tid;
    int ds = flat & 3, n = flat >> 2;
    int rev = __brev((unsigned)n) >> 22;   // 10-bit reversal
    size_t ga = (size_t)(dc * FD + ds) * out_sd + (size_t)n * out_sn;
    oR[ga] = lr[ds][rev] * 0.03125f;
    oI[ga] = li[ds][rev] * 0.03125f;
  }
}

// ============================================================
// Fourier attention:  scores = 0.125 * Re(Qf . conj(Kf)) ; softmax ;
// out = attn @ Vf (real weights on complex V).
// Block = 256 threads handles 8 q-rows of one (b,h). Two-pass softmax,
// K staged in LDS one plane at a time (KT stored [dh][N], coalesced).
// ============================================================
__global__ __launch_bounds__(256) void attn_kernel(
    const float* __restrict__ Qr, const float* __restrict__ Qi,   // [BH,N,64]
    const float* __restrict__ KTr, const float* __restrict__ KTi, // [BH,64,N]
    const float* __restrict__ Vr, const float* __restrict__ Vi,   // [BH,N,64]
    float* __restrict__ Or, float* __restrict__ Oi)               // [BH,N,64]
{
  __shared__ float q[8][128];      // 8 rows x (qr|qi)
  __shared__ float kt[64][64];     // one plane of a 64-wide m tile
  __shared__ float p[8][1024];     // scores / probs
  __shared__ float sinv[8];
  const int tid = threadIdx.x;
  const int bh = blockIdx.x >> 7;         // 128 row-groups per bh
  const int n0 = (blockIdx.x & 127) * 8;
  const size_t qbase = ((size_t)bh * NN + n0) * DHH;
  for (int t = tid; t < 8 * 64; t += 256) {
    int r = t >> 6, d = t & 63;
    q[r][d]      = Qr[qbase + (size_t)r * DHH + d];
    q[r][64 + d] = Qi[qbase + (size_t)r * DHH + d];
  }
  __syncthreads();
  const int rq = tid >> 5;   // 0..7
  const int ml = tid & 31;   // 0..31
  const size_t kbase = (size_t)bh * DHH * NN;
  for (int m0 = 0; m0 < NN; m0 += 64) {
    float acc0 = 0.f, acc1 = 0.f;
    // ---- real plane ----
    for (int t = tid; t < 64 * 64; t += 256) {
      int d = t >> 6, j = t & 63;
      kt[d][j] = KTr[kbase + (size_t)d * NN + m0 + j];
    }
    __syncthreads();
#pragma unroll 8
    for (int d = 0; d < 64; ++d) {
      float qv = q[rq][d];
      acc0 += qv * kt[d][ml];
      acc1 += qv * kt[d][ml + 32];
    }
    __syncthreads();
    // ---- imag plane ----
    for (int t = tid; t < 64 * 64; t += 256) {
      int d = t >> 6, j = t & 63;
      kt[d][j] = KTi[kbase + (size_t)d * NN + m0 + j];
    }
    __syncthreads();
#pragma unroll 8
    for (int d = 0; d < 64; ++d) {
      float qv = q[rq][64 + d];
      acc0 += qv * kt[d][ml];
      acc1 += qv * kt[d][ml + 32];
    }
    __syncthreads();
    p[rq][m0 + ml]      = acc0 * 0.125f;
    p[rq][m0 + ml + 32] = acc1 * 0.125f;
  }
  __syncthreads();
  // ---- softmax over each row (32 lanes per row) ----
  float mx = -1e30f;
#pragma unroll
  for (int k = 0; k < 32; ++k) mx = fmaxf(mx, p[rq][ml + 32 * k]);
#pragma unroll
  for (int o = 16; o; o >>= 1) mx = fmaxf(mx, __shfl_xor(mx, o));
  float sum = 0.f;
#pragma unroll
  for (int k = 0; k < 32; ++k) {
    float e = __expf(p[rq][ml + 32 * k] - mx);
    p[rq][ml + 32 * k] = e;
    sum += e;
  }
#pragma unroll
  for (int o = 16; o; o >>= 1) sum += __shfl_xor(sum, o);
  if (ml == 0) sinv[rq] = 1.f / sum;
  __syncthreads();
  // ---- PV: out[8][128] (64 real | 64 imag cols) ----
  const int c = tid & 127;
  const int rr = (tid >> 7) * 4;
  const int cc = c & 63;
  const float* Vp = (c < 64) ? Vr : Vi;
  const size_t vbase = (size_t)bh * NN * DHH + cc;
  float acc[4] = {0.f, 0.f, 0.f, 0.f};
  for (int m = 0; m < NN; ++m) {
    float v = Vp[vbase + (size_t)m * DHH];
    acc[0] += p[rr + 0][m] * v;
    acc[1] += p[rr + 1][m] * v;
    acc[2] += p[rr + 2][m] * v;
    acc[3] += p[rr + 3][m] * v;
  }
  float* Op = (c < 64) ? Or : Oi;
  const size_t obase = ((size_t)bh * NN + n0) * DHH + cc;
#pragma unroll
  for (int k = 0; k < 4; ++k)
    Op[obase + (size_t)(rr + k) * DHH] = acc[k] * sinv[rr + k];
}

// ============================================================
// Host-side orchestration
// ============================================================
extern "C" void kernel_launch(void* const* d_in, const int* in_sizes, int n_in,
                              void* d_out, int out_size, void* d_ws, size_t ws_size,
                              hipStream_t stream) {
  const float* xr   = (const float*)d_in[0];
  const float* xi   = (const float*)d_in[1];
  const float* Wqr  = (const float*)d_in[2];
  const float* Wqi  = (const float*)d_in[3];
  const float* bqr  = (const float*)d_in[4];
  const float* bqi  = (const float*)d_in[5];
  const float* Wkr  = (const float*)d_in[6];
  const float* Wki  = (const float*)d_in[7];
  const float* bkr  = (const float*)d_in[8];
  const float* bki  = (const float*)d_in[9];
  const float* Wvr  = (const float*)d_in[10];
  const float* Wvi  = (const float*)d_in[11];
  const float* bvr  = (const float*)d_in[12];
  const float* bvi  = (const float*)d_in[13];
  const float* Wor  = (const float*)d_in[14];
  const float* Woi  = (const float*)d_in[15];
  const float* bor  = (const float*)d_in[16];
  const float* boi  = (const float*)d_in[17];
  const float* gq   = (const float*)d_in[18];
  const float* beq  = (const float*)d_in[19];
  const float* gk   = (const float*)d_in[20];
  const float* bek  = (const float*)d_in[21];
  const float* gv   = (const float*)d_in[22];
  const float* bev  = (const float*)d_in[23];

  float* ws = (float*)d_ws;
  const size_t PL = (size_t)BN * DIMM;   // 4,194,304 floats per plane
  float* Ar  = ws + 0 * PL;   // working pair (proj/cln, later attn-out)
  float* Ai  = ws + 1 * PL;
  float* Qfr = ws + 2 * PL;   // later reused as iFFT output
  float* Qfi = ws + 3 * PL;
  float* KTr = ws + 4 * PL;
  float* KTi = ws + 5 * PL;
  float* Vfr = ws + 6 * PL;
  float* Vfi = ws + 7 * PL;

  const dim3 gGemm(DIMM / TS, BN / TS);  // (16, 64)
  const int gCln = BN;                   // 4096 rows
  const int gFft = 64 * 16;              // bh * d-chunks
  const int gAtt = 64 * 128;             // bh * row-groups

  // ---- Q ----
  cgemm_nt<<<gGemm, 256, 0, stream>>>(xr, xi, Wqr, Wqi, bqr, bqi, Ar, Ai, DIMM);
  cln_kernel<<<gCln, 256, 0, stream>>>(Ar, Ai, gq, beq);
  fft_kernel<<<gFft, 512, 0, stream>>>(Ar, Ai, Qfr, Qfi,
      NN * DIMM, DHH, DIMM, 1,     // in: [B,N,DIM] head gather
      16 * NN * DHH, NN * DHH, DHH, 1,   // out: [BH,N,64]
      -1.0f);
  // ---- K (output transposed [BH,64,N]) ----
  cgemm_nt<<<gGemm, 256, 0, stream>>>(xr, xi, Wkr, Wki, bkr, bki, Ar, Ai, DIMM);
  cln_kernel<<<gCln, 256, 0, stream>>>(Ar, Ai, gk, bek);
  fft_kernel<<<gFft, 512, 0, stream>>>(Ar, Ai, KTr, KTi,
      NN * DIMM, DHH, DIMM, 1,
      16 * NN * DHH, NN * DHH, 1, NN,    // out: [BH,64,N]
      -1.0f);
  // ---- V ----
  cgemm_nt<<<gGemm, 256, 0, stream>>>(xr, xi, Wvr, Wvi, bvr, bvi, Ar, Ai, DIMM);
  cln_kernel<<<gCln, 256, 0, stream>>>(Ar, Ai, gv, bev);
  fft_kernel<<<gFft, 512, 0, stream>>>(Ar, Ai, Vfr, Vfi,
      NN * DIMM, DHH, DIMM, 1,
      16 * NN * DHH, NN * DHH, DHH, 1,
      -1.0f);
  // ---- attention (writes Ar/Ai = out_f) ----
  attn_kernel<<<gAtt, 256, 0, stream>>>(Qfr, Qfi, KTr, KTi, Vfr, Vfi, Ar, Ai);
  // ---- inverse FFT: out_f -> [B,N,DIM] complex (reuse Qf planes) ----
  fft_kernel<<<gFft, 512, 0, stream>>>(Ar, Ai, Qfr, Qfi,
      16 * NN * DHH, NN * DHH, DHH, 1,   // in: [BH,N,64]
      NN * DIMM, DHH, DIMM, 1,           // out: [B,N,DIM] head scatter
      +1.0f);
  // ---- output projection straight into d_out ([B,N, real||imag]) ----
  float* yout = (float*)d_out;
  cgemm_nt<<<gGemm, 256, 0, stream>>>(Qfr, Qfi, Wor, Woi, bor, boi,
                                      yout, yout + DIMM, 2 * DIMM);
}

// Round 3
// 900.706 us; speedup vs baseline: 4.9821x; 4.9821x over previous
//
#include <hip/hip_runtime.h>
#include <math.h>

#define BB 4
#define NN 1024
#define DIMM 1024
#define HHH 16
#define DHH 64
#define BN 4096            // B*N rows
#define EPS_LN 1e-6f

typedef __bf16 bf16_t;
typedef __bf16 bf16x8 __attribute__((ext_vector_type(8)));
typedef float f32x4 __attribute__((ext_vector_type(4)));
#define MFMA16(a, b, c) __builtin_amdgcn_mfma_f32_16x16x32_bf16(a, b, c, 0, 0, 0)

// ============================================================
// pack_x: Axaug[4096][2048] = bf16([xr | xi])
// ============================================================
__global__ __launch_bounds__(256) void pack_x(
    const float* __restrict__ xr, const float* __restrict__ xi,
    bf16_t* __restrict__ out)
{
  int t = blockIdx.x * 256 + threadIdx.x;
  size_t e = (size_t)t * 8;
  int row = (int)(e >> 11), col = (int)(e & 2047);
  const float* src = (col < 1024) ? (xr + (size_t)row * 1024 + col)
                                  : (xi + (size_t)row * 1024 + col - 1024);
  float4 a = *(const float4*)src;
  float4 b = *(const float4*)(src + 4);
  bf16x8 o;
  o[0] = (bf16_t)a.x; o[1] = (bf16_t)a.y; o[2] = (bf16_t)a.z; o[3] = (bf16_t)a.w;
  o[4] = (bf16_t)b.x; o[5] = (bf16_t)b.y; o[6] = (bf16_t)b.z; o[7] = (bf16_t)b.w;
  *(bf16x8*)(out + e) = o;
}

// ============================================================
// pack_w: Wcat[2048][2048]: rows 0-1023 = [Wr | -Wi], rows 1024-2047 = [Wi | Wr]
//         bcat[2048] = [br | bi]
// ============================================================
__global__ __launch_bounds__(256) void pack_w(
    const float* __restrict__ Wr, const float* __restrict__ Wi,
    const float* __restrict__ br, const float* __restrict__ bi,
    bf16_t* __restrict__ Wcat, float* __restrict__ bcat)
{
  int t = blockIdx.x * 256 + threadIdx.x;
  size_t e = (size_t)t * 8;
  int row = (int)(e >> 11), col = (int)(e & 2047);
  const float* src;
  float sgn = 1.f;
  if (row < 1024) {
    if (col < 1024) src = Wr + (size_t)row * 1024 + col;
    else          { src = Wi + (size_t)row * 1024 + col - 1024; sgn = -1.f; }
  } else {
    int r2 = row - 1024;
    if (col < 1024) src = Wi + (size_t)r2 * 1024 + col;
    else            src = Wr + (size_t)r2 * 1024 + col - 1024;
  }
  float4 a = *(const float4*)src;
  float4 b = *(const float4*)(src + 4);
  bf16x8 o;
  o[0] = (bf16_t)(sgn * a.x); o[1] = (bf16_t)(sgn * a.y);
  o[2] = (bf16_t)(sgn * a.z); o[3] = (bf16_t)(sgn * a.w);
  o[4] = (bf16_t)(sgn * b.x); o[5] = (bf16_t)(sgn * b.y);
  o[6] = (bf16_t)(sgn * b.z); o[7] = (bf16_t)(sgn * b.w);
  *(bf16x8*)(Wcat + e) = o;
  if (e < 2048) {
#pragma unroll
    for (int j = 0; j < 8; ++j) {
      int n = (int)e + j;
      bcat[n] = (n < 1024) ? br[n] : bi[n - 1024];
    }
  }
}

// ============================================================
// bf16 MFMA GEMM (NT): C = A[4096][2048] @ Bt[2048][2048]^T + bias
// 128x128 tile, 4 waves (2x2), 16x16x32 MFMA, BK=64, padded LDS.
// Output col n<1024 -> Cr, else Ci (col-1024).
// ============================================================
__global__ __launch_bounds__(256) void gemm_bf16(
    const bf16_t* __restrict__ A, const bf16_t* __restrict__ Bt,
    const float* __restrict__ bias,
    float* __restrict__ Cr, float* __restrict__ Ci, int ldc)
{
  __shared__ bf16_t sA[128][72];
  __shared__ bf16_t sB[128][72];
  const int tid = threadIdx.x;
  const int w = tid >> 6, l = tid & 63;
  const int lo4 = l & 15, hi = l >> 4;
  const int wr = w >> 1, wc = w & 1;
  const int row0 = blockIdx.y * 128, col0 = blockIdx.x * 128;
  f32x4 acc[4][4] = {};
  for (int k0 = 0; k0 < 2048; k0 += 64) {
    __syncthreads();
    for (int c = tid; c < 1024; c += 256) {
      int r = c >> 3, cc = c & 7;
      *(bf16x8*)&sA[r][cc * 8] =
          *(const bf16x8*)&A[(size_t)(row0 + r) * 2048 + k0 + cc * 8];
    }
    for (int c = tid; c < 1024; c += 256) {
      int r = c >> 3, cc = c & 7;
      *(bf16x8*)&sB[r][cc * 8] =
          *(const bf16x8*)&Bt[(size_t)(col0 + r) * 2048 + k0 + cc * 8];
    }
    __syncthreads();
#pragma unroll
    for (int kk = 0; kk < 2; ++kk) {
      bf16x8 am[4], bn[4];
#pragma unroll
      for (int i = 0; i < 4; ++i)
        am[i] = *(const bf16x8*)&sA[wr * 64 + i * 16 + lo4][kk * 32 + hi * 8];
#pragma unroll
      for (int j = 0; j < 4; ++j)
        bn[j] = *(const bf16x8*)&sB[wc * 64 + j * 16 + lo4][kk * 32 + hi * 8];
#pragma unroll
      for (int i = 0; i < 4; ++i)
#pragma unroll
        for (int j = 0; j < 4; ++j)
          acc[i][j] = MFMA16(am[i], bn[j], acc[i][j]);
    }
  }
  const int colg0 = col0 + wc * 64;
  float* Cp = (colg0 < 1024) ? Cr : Ci;
  const int cb = colg0 & 1023;
#pragma unroll
  for (int i = 0; i < 4; ++i) {
#pragma unroll
    for (int j = 0; j < 4; ++j) {
      float bv = bias[colg0 + j * 16 + lo4];
#pragma unroll
      for (int r = 0; r < 4; ++r) {
        int rowg = row0 + wr * 64 + i * 16 + hi * 4 + r;
        Cp[(size_t)rowg * ldc + cb + j * 16 + lo4] = acc[i][j][r] + bv;
      }
    }
  }
}

// ============================================================
// Complex LayerNorm (unchanged, fp32 in-place)
// ============================================================
__global__ __launch_bounds__(256) void cln_kernel(
    float* __restrict__ re, float* __restrict__ im,
    const float* __restrict__ gamma, const float* __restrict__ beta)
{
  __shared__ float red[8];
  const int row = blockIdx.x;
  const int tid = threadIdx.x;
  float* pr = re + (size_t)row * DIMM;
  float* pi = im + (size_t)row * DIMM;
  float vr[4], vi[4], mg[4];
  float s = 0.f, s2 = 0.f;
#pragma unroll
  for (int t = 0; t < 4; ++t) {
    int c = tid + t * 256;
    vr[t] = pr[c]; vi[t] = pi[c];
    mg[t] = sqrtf(vr[t] * vr[t] + vi[t] * vi[t]);
    s += mg[t]; s2 += mg[t] * mg[t];
  }
#pragma unroll
  for (int o = 32; o; o >>= 1) { s += __shfl_down(s, o); s2 += __shfl_down(s2, o); }
  if ((tid & 63) == 0) { red[tid >> 6] = s; red[4 + (tid >> 6)] = s2; }
  __syncthreads();
  if (tid == 0) {
    float S = red[0] + red[1] + red[2] + red[3];
    float S2 = red[4] + red[5] + red[6] + red[7];
    float mean = S * (1.f / DIMM);
    float var = S2 * (1.f / DIMM) - mean * mean;
    red[0] = mean;
    red[1] = rsqrtf(var + EPS_LN);
  }
  __syncthreads();
  float mean = red[0], inv = red[1];
#pragma unroll
  for (int t = 0; t < 4; ++t) {
    int c = tid + t * 256;
    float nm = (mg[t] - mean) * inv * gamma[c] + beta[c];
    float invm = mg[t] > 0.f ? 1.f / mg[t] : 0.f;
    float cr = mg[t] > 0.f ? vr[t] * invm : 1.f;
    float ci = mg[t] > 0.f ? vi[t] * invm : 0.f;
    pr[c] = nm * cr;
    pi[c] = nm * ci;
  }
}

// ============================================================
// 1024-pt radix-2 DIF FFT, ortho norm; fp32 in, bf16 out, stride-parametrized.
// ============================================================
#define FD 4
__global__ __launch_bounds__(512) void fft_kernel(
    const float* __restrict__ inR, const float* __restrict__ inI,
    bf16_t* __restrict__ outR, bf16_t* __restrict__ outI,
    int in_sb, int in_sh, int in_sn, int in_sd,
    int out_sb, int out_sh, int out_sn, int out_sd,
    float sign)
{
  __shared__ float lr[FD][NN + 1], li[FD][NN + 1];
  const int tid = threadIdx.x;
  const int dc = blockIdx.x & 15;
  const int bh = blockIdx.x >> 4;
  const int b = bh >> 4, h = bh & 15;
  const float* bR = inR + (size_t)b * in_sb + (size_t)h * in_sh;
  const float* bI = inI + (size_t)b * in_sb + (size_t)h * in_sh;
#pragma unroll
  for (int it = 0; it < 8; ++it) {
    int flat = it * 512 + tid;
    int ds = flat & 3, n = flat >> 2;
    size_t ga = (size_t)(dc * FD + ds) * in_sd + (size_t)n * in_sn;
    lr[ds][n] = bR[ga];
    li[ds][n] = bI[ga];
  }
  __syncthreads();
  const int dsub = tid & 3;
  const int jb = tid >> 2;
  for (int hs = 9; hs >= 0; --hs) {
    int half = 1 << hs;
    float angstep = sign * 3.14159265358979323846f / (float)half;
#pragma unroll
    for (int it = 0; it < 4; ++it) {
      int j = jb + it * 128;
      int o = j & (half - 1);
      int i0 = ((j >> hs) << (hs + 1)) + o;
      int i1 = i0 + half;
      float ar = lr[dsub][i0], ai = li[dsub][i0];
      float br_ = lr[dsub][i1], bi_ = li[dsub][i1];
      lr[dsub][i0] = ar + br_;
      li[dsub][i0] = ai + bi_;
      float sr = ar - br_, si = ai - bi_;
      float sn, cs;
      __sincosf(angstep * (float)o, &sn, &cs);
      lr[dsub][i1] = sr * cs - si * sn;
      li[dsub][i1] = sr * sn + si * cs;
    }
    __syncthreads();
  }
  bf16_t* oR = outR + (size_t)b * out_sb + (size_t)h * out_sh;
  bf16_t* oI = outI + (size_t)b * out_sb + (size_t)h * out_sh;
#pragma unroll
  for (int it = 0; it < 8; ++it) {
    int flat = it * 512 + tid;
    int ds = flat & 3, n = flat >> 2;
    int rev = __brev((unsigned)n) >> 22;
    size_t ga = (size_t)(dc * FD + ds) * out_sd + (size_t)n * out_sn;
    oR[ga] = (bf16_t)(lr[ds][rev] * 0.03125f);
    oI[ga] = (bf16_t)(li[ds][rev] * 0.03125f);
  }
}

// ============================================================
// Flash attention, bf16 MFMA, d=128 real attention in Fourier space.
// Qf,Kf: [BH,N,128] (r|i packed); VfT: [BH,128,N] (d-major).
// Block = 4 waves x 16 q-rows = 64 q-rows. KV tiles of 32, online softmax.
// Or/Oi: fp32 [BH,N,64].
// ============================================================
__global__ __launch_bounds__(256) void fattn(
    const bf16_t* __restrict__ Qf, const bf16_t* __restrict__ Kf,
    const bf16_t* __restrict__ VfT,
    float* __restrict__ Or, float* __restrict__ Oi)
{
  __shared__ bf16_t sK[32][136];     // kv-tile [32][128] padded
  __shared__ bf16_t sVT[128][40];    // V^T tile [128 d][32 kv] padded
  __shared__ bf16_t pbuf[4][16][40]; // per-wave P transpose buffer
  const int tid = threadIdx.x;
  const int w = tid >> 6, l = tid & 63;
  const int lo4 = l & 15, hi = l >> 4;
  const int bh = blockIdx.x >> 4;
  const int q0 = (blockIdx.x & 15) * 64;

  // Q fragments (A-layout): row=lo4, k=hi*8+j within each 32-wide k window
  bf16x8 aq[4];
  const bf16_t* qp = Qf + (((size_t)bh * NN + q0 + w * 16 + lo4) * 128) + hi * 8;
#pragma unroll
  for (int kk = 0; kk < 4; ++kk) aq[kk] = *(const bf16x8*)(qp + kk * 32);

  f32x4 o[8] = {};
  float m[4] = {-3e38f, -3e38f, -3e38f, -3e38f};
  float ln[4] = {0.f, 0.f, 0.f, 0.f};

  const size_t kbase = (size_t)bh * NN * 128;
  const size_t vbase = (size_t)bh * 128 * NN;

  for (int kv0 = 0; kv0 < NN; kv0 += 32) {
    __syncthreads();   // protect prior tile reads
    // stage K [32][128]
    for (int c = tid; c < 512; c += 256) {
      int r = c >> 4, cc = c & 15;
      *(bf16x8*)&sK[r][cc * 8] =
          *(const bf16x8*)&Kf[kbase + (size_t)(kv0 + r) * 128 + cc * 8];
    }
    // stage V^T [128 d][32 kv] from VfT (already d-major)
    for (int c = tid; c < 512; c += 256) {
      int d = c >> 2, kc = c & 3;
      *(bf16x8*)&sVT[d][kc * 8] =
          *(const bf16x8*)&VfT[vbase + (size_t)d * NN + kv0 + kc * 8];
    }
    __syncthreads();

    // S = Q . K^T  (two 16-col fragments covering 32 kv)
    f32x4 s0 = {}, s1 = {};
#pragma unroll
    for (int kk = 0; kk < 4; ++kk) {
      bf16x8 b0 = *(const bf16x8*)&sK[lo4][kk * 32 + hi * 8];
      bf16x8 b1 = *(const bf16x8*)&sK[16 + lo4][kk * 32 + hi * 8];
      s0 = MFMA16(aq[kk], b0, s0);
      s1 = MFMA16(aq[kk], b1, s1);
    }
    // online softmax update (rows = hi*4 + r)
    float alpha[4];
#pragma unroll
    for (int r = 0; r < 4; ++r) {
      float a0 = s0[r] * 0.125f, a1 = s1[r] * 0.125f;
      float mx = fmaxf(a0, a1);
      mx = fmaxf(mx, __shfl_xor(mx, 1));
      mx = fmaxf(mx, __shfl_xor(mx, 2));
      mx = fmaxf(mx, __shfl_xor(mx, 4));
      mx = fmaxf(mx, __shfl_xor(mx, 8));
      float mnew = fmaxf(m[r], mx);
      float al = __expf(m[r] - mnew);
      float p0 = __expf(a0 - mnew);
      float p1 = __expf(a1 - mnew);
      s0[r] = p0; s1[r] = p1;
      float rs = p0 + p1;
      rs += __shfl_xor(rs, 1);
      rs += __shfl_xor(rs, 2);
      rs += __shfl_xor(rs, 4);
      rs += __shfl_xor(rs, 8);
      ln[r] = ln[r] * al + rs;
      m[r] = mnew;
      alpha[r] = al;
    }
#pragma unroll
    for (int f = 0; f < 8; ++f) {
      o[f][0] *= alpha[0]; o[f][1] *= alpha[1];
      o[f][2] *= alpha[2]; o[f][3] *= alpha[3];
    }
    // P (C-layout) -> pbuf[q][kv] -> A-fragment
#pragma unroll
    for (int r = 0; r < 4; ++r) {
      pbuf[w][hi * 4 + r][lo4]      = (bf16_t)s0[r];
      pbuf[w][hi * 4 + r][16 + lo4] = (bf16_t)s1[r];
    }
    bf16x8 pa = *(const bf16x8*)&pbuf[w][lo4][hi * 8];
    // PV: O += P(16x32) . V(32x128)
#pragma unroll
    for (int d0 = 0; d0 < 8; ++d0) {
      bf16x8 bv = *(const bf16x8*)&sVT[d0 * 16 + lo4][hi * 8];
      o[d0] = MFMA16(pa, bv, o[d0]);
    }
  }
  // normalize + store
#pragma unroll
  for (int r = 0; r < 4; ++r) {
    float inv = 1.f / ln[r];
    int qrow = q0 + w * 16 + hi * 4 + r;
    size_t base = ((size_t)bh * NN + qrow) * 64;
#pragma unroll
    for (int d0 = 0; d0 < 8; ++d0) {
      float val = o[d0][r] * inv;
      int col = d0 * 16 + lo4;
      if (col < 64) Or[base + col] = val;
      else          Oi[base + col - 64] = val;
    }
  }
}

// ============================================================
// Host-side orchestration
// ============================================================
extern "C" void kernel_launch(void* const* d_in, const int* in_sizes, int n_in,
                              void* d_out, int out_size, void* d_ws, size_t ws_size,
                              hipStream_t stream) {
  const float* xr   = (const float*)d_in[0];
  const float* xi   = (const float*)d_in[1];
  const float* Wqr  = (const float*)d_in[2];
  const float* Wqi  = (const float*)d_in[3];
  const float* bqr  = (const float*)d_in[4];
  const float* bqi  = (const float*)d_in[5];
  const float* Wkr  = (const float*)d_in[6];
  const float* Wki  = (const float*)d_in[7];
  const float* bkr  = (const float*)d_in[8];
  const float* bki  = (const float*)d_in[9];
  const float* Wvr  = (const float*)d_in[10];
  const float* Wvi  = (const float*)d_in[11];
  const float* bvr  = (const float*)d_in[12];
  const float* bvi  = (const float*)d_in[13];
  const float* Wor  = (const float*)d_in[14];
  const float* Woi  = (const float*)d_in[15];
  const float* bor  = (const float*)d_in[16];
  const float* boi  = (const float*)d_in[17];
  const float* gq   = (const float*)d_in[18];
  const float* beq  = (const float*)d_in[19];
  const float* gk   = (const float*)d_in[20];
  const float* bek  = (const float*)d_in[21];
  const float* gv   = (const float*)d_in[22];
  const float* bev  = (const float*)d_in[23];

  char* wp = (char*)d_ws;
  bf16_t* Axaug = (bf16_t*)wp;  wp += (size_t)4096 * 2048 * 2;   // 16.78 MB
  bf16_t* Wcat  = (bf16_t*)wp;  wp += (size_t)2048 * 2048 * 2;   // 8.39 MB
  float*  bcat  = (float*)wp;   wp += (size_t)2048 * 4;
  float*  Ar    = (float*)wp;   wp += (size_t)4096 * 1024 * 4;   // 16.78 MB
  float*  Ai    = (float*)wp;   wp += (size_t)4096 * 1024 * 4;
  bf16_t* Qf    = (bf16_t*)wp;  wp += (size_t)64 * 1024 * 128 * 2;
  bf16_t* Kf    = (bf16_t*)wp;  wp += (size_t)64 * 1024 * 128 * 2;
  bf16_t* VfT   = (bf16_t*)wp;  wp += (size_t)64 * 1024 * 128 * 2;
  bf16_t* Yaug  = Qf;  // reuse after attention

  const dim3 gGemm(16, 32);           // 2048/128 x 4096/128
  const int gPackX = (4096 * 2048 / 8) / 256;  // 4096
  const int gPackW = (2048 * 2048 / 8) / 256;  // 2048
  const int gCln = BN;
  const int gFft = 64 * 16;
  const int gAtt = 64 * 16;

  pack_x<<<gPackX, 256, 0, stream>>>(xr, xi, Axaug);

  // ---- Q ----
  pack_w<<<gPackW, 256, 0, stream>>>(Wqr, Wqi, bqr, bqi, Wcat, bcat);
  gemm_bf16<<<gGemm, 256, 0, stream>>>(Axaug, Wcat, bcat, Ar, Ai, 1024);
  cln_kernel<<<gCln, 256, 0, stream>>>(Ar, Ai, gq, beq);
  fft_kernel<<<gFft, 512, 0, stream>>>(Ar, Ai, Qf, Qf + 64,
      NN * DIMM, DHH, DIMM, 1,
      16 * NN * 128, NN * 128, 128, 1, -1.0f);
  // ---- K ----
  pack_w<<<gPackW, 256, 0, stream>>>(Wkr, Wki, bkr, bki, Wcat, bcat);
  gemm_bf16<<<gGemm, 256, 0, stream>>>(Axaug, Wcat, bcat, Ar, Ai, 1024);
  cln_kernel<<<gCln, 256, 0, stream>>>(Ar, Ai, gk, bek);
  fft_kernel<<<gFft, 512, 0, stream>>>(Ar, Ai, Kf, Kf + 64,
      NN * DIMM, DHH, DIMM, 1,
      16 * NN * 128, NN * 128, 128, 1, -1.0f);
  // ---- V (transposed output [BH,128,N]) ----
  pack_w<<<gPackW, 256, 0, stream>>>(Wvr, Wvi, bvr, bvi, Wcat, bcat);
  gemm_bf16<<<gGemm, 256, 0, stream>>>(Axaug, Wcat, bcat, Ar, Ai, 1024);
  cln_kernel<<<gCln, 256, 0, stream>>>(Ar, Ai, gv, bev);
  fft_kernel<<<gFft, 512, 0, stream>>>(Ar, Ai, VfT, VfT + (size_t)64 * NN,
      NN * DIMM, DHH, DIMM, 1,
      16 * 128 * NN, 128 * NN, 1, NN, -1.0f);
  // ---- flash attention -> Or/Oi (reuse Ar/Ai planes as [BH,N,64]) ----
  fattn<<<gAtt, 256, 0, stream>>>(Qf, Kf, VfT, Ar, Ai);
  // ---- inverse FFT -> Yaug bf16 [4096][2048] (head scatter + r|i halves) ----
  fft_kernel<<<gFft, 512, 0, stream>>>(Ar, Ai, Yaug, Yaug + 1024,
      16 * NN * 64, NN * 64, 64, 1,
      NN * 2048, 64, 2048, 1, +1.0f);
  // ---- output projection straight into d_out ----
  float* yout = (float*)d_out;
  pack_w<<<gPackW, 256, 0, stream>>>(Wor, Woi, bor, boi, Wcat, bcat);
  gemm_bf16<<<gGemm, 256, 0, stream>>>(Yaug, Wcat, bcat, yout, yout + 1024, 2048);
}

// Round 4
// 664.590 us; speedup vs baseline: 6.7522x; 1.3553x over previous
//
#include <hip/hip_runtime.h>
#include <math.h>

#define BB 4
#define NN 1024
#define DIMM 1024
#define HHH 16
#define DHH 64
#define BN 4096            // B*N rows
#define EPS_LN 1e-6f

typedef __bf16 bf16_t;
typedef __bf16 bf16x8 __attribute__((ext_vector_type(8)));
typedef float f32x4 __attribute__((ext_vector_type(4)));
#define MFMA16(a, b, c) __builtin_amdgcn_mfma_f32_16x16x32_bf16(a, b, c, 0, 0, 0)
#define AS1 __attribute__((address_space(1)))
#define AS3 __attribute__((address_space(3)))

// ============================================================
// pack_x: Axaug[4096][2048] = bf16([xr | xi])
// ============================================================
__global__ __launch_bounds__(256) void pack_x(
    const float* __restrict__ xr, const float* __restrict__ xi,
    bf16_t* __restrict__ out)
{
  int t = blockIdx.x * 256 + threadIdx.x;
  size_t e = (size_t)t * 8;
  int row = (int)(e >> 11), col = (int)(e & 2047);
  const float* src = (col < 1024) ? (xr + (size_t)row * 1024 + col)
                                  : (xi + (size_t)row * 1024 + col - 1024);
  float4 a = *(const float4*)src;
  float4 b = *(const float4*)(src + 4);
  bf16x8 o;
  o[0] = (bf16_t)a.x; o[1] = (bf16_t)a.y; o[2] = (bf16_t)a.z; o[3] = (bf16_t)a.w;
  o[4] = (bf16_t)b.x; o[5] = (bf16_t)b.y; o[6] = (bf16_t)b.z; o[7] = (bf16_t)b.w;
  *(bf16x8*)(out + e) = o;
}

// ============================================================
// pack_w: Wcat[2048][2048]: rows 0-1023 = [Wr | -Wi], rows 1024-2047 = [Wi | Wr]
// ============================================================
__global__ __launch_bounds__(256) void pack_w(
    const float* __restrict__ Wr, const float* __restrict__ Wi,
    const float* __restrict__ br, const float* __restrict__ bi,
    bf16_t* __restrict__ Wcat, float* __restrict__ bcat)
{
  int t = blockIdx.x * 256 + threadIdx.x;
  size_t e = (size_t)t * 8;
  int row = (int)(e >> 11), col = (int)(e & 2047);
  const float* src;
  float sgn = 1.f;
  if (row < 1024) {
    if (col < 1024) src = Wr + (size_t)row * 1024 + col;
    else          { src = Wi + (size_t)row * 1024 + col - 1024; sgn = -1.f; }
  } else {
    int r2 = row - 1024;
    if (col < 1024) src = Wi + (size_t)r2 * 1024 + col;
    else            src = Wr + (size_t)r2 * 1024 + col - 1024;
  }
  float4 a = *(const float4*)src;
  float4 b = *(const float4*)(src + 4);
  bf16x8 o;
  o[0] = (bf16_t)(sgn * a.x); o[1] = (bf16_t)(sgn * a.y);
  o[2] = (bf16_t)(sgn * a.z); o[3] = (bf16_t)(sgn * a.w);
  o[4] = (bf16_t)(sgn * b.x); o[5] = (bf16_t)(sgn * b.y);
  o[6] = (bf16_t)(sgn * b.z); o[7] = (bf16_t)(sgn * b.w);
  *(bf16x8*)(Wcat + e) = o;
  if (e < 2048) {
#pragma unroll
    for (int j = 0; j < 8; ++j) {
      int n = (int)e + j;
      bcat[n] = (n < 1024) ? br[n] : bi[n - 1024];
    }
  }
}

// ============================================================
// bf16 MFMA GEMM (NT), m97 structure: 128x128 tile, BK=64, 4 waves (2x2),
// LINEAR LDS + global_load_lds width=16 staging.
// C = A[4096][2048] @ Bt[2048][2048]^T + bias; col<1024 -> Cr else Ci.
// ============================================================
__global__ __launch_bounds__(256) void gemm_bf16(
    const bf16_t* __restrict__ A, const bf16_t* __restrict__ Bt,
    const float* __restrict__ bias,
    float* __restrict__ Cr, float* __restrict__ Ci, int ldc)
{
  __shared__ bf16_t sA[128 * 64];
  __shared__ bf16_t sB[128 * 64];
  const int tid = threadIdx.x;
  const int w = tid >> 6, l = tid & 63;
  const int lo4 = l & 15, hi = l >> 4;
  const int wr = w >> 1, wc = w & 1;
  const int row0 = blockIdx.y * 128, col0 = blockIdx.x * 128;

  // staging source pointers: wave w, sub-issue i covers tile rows (w*4+i)*8..+7
  const int srow = (l >> 3);           // 0..7 within 8-row stripe
  const int scol = (l & 7) * 8;        // 0..56, 16B-aligned element col
  const bf16_t* gA[4];
  const bf16_t* gB[4];
#pragma unroll
  for (int i = 0; i < 4; ++i) {
    int r = (w * 4 + i) * 8 + srow;
    gA[i] = A  + (size_t)(row0 + r) * 2048 + scol;
    gB[i] = Bt + (size_t)(col0 + r) * 2048 + scol;
  }

  f32x4 acc[4][4] = {};
  for (int k0 = 0; k0 < 2048; k0 += 64) {
    __syncthreads();                    // prior compute done before overwrite
#pragma unroll
    for (int i = 0; i < 4; ++i) {
      __builtin_amdgcn_global_load_lds((const AS1 void*)(gA[i] + k0),
                                       (AS3 void*)&sA[(w * 4 + i) * 512], 16, 0, 0);
      __builtin_amdgcn_global_load_lds((const AS1 void*)(gB[i] + k0),
                                       (AS3 void*)&sB[(w * 4 + i) * 512], 16, 0, 0);
    }
    __syncthreads();                    // compiler drains vmcnt(0) here
#pragma unroll
    for (int kk = 0; kk < 2; ++kk) {
      bf16x8 am[4], bn[4];
#pragma unroll
      for (int i = 0; i < 4; ++i)
        am[i] = *(const bf16x8*)&sA[(wr * 64 + i * 16 + lo4) * 64 + kk * 32 + hi * 8];
#pragma unroll
      for (int j = 0; j < 4; ++j)
        bn[j] = *(const bf16x8*)&sB[(wc * 64 + j * 16 + lo4) * 64 + kk * 32 + hi * 8];
#pragma unroll
      for (int i = 0; i < 4; ++i)
#pragma unroll
        for (int j = 0; j < 4; ++j)
          acc[i][j] = MFMA16(am[i], bn[j], acc[i][j]);
    }
  }
  const int colg0 = col0 + wc * 64;
  float* Cp = (colg0 < 1024) ? Cr : Ci;
  const int cb = colg0 & 1023;
#pragma unroll
  for (int i = 0; i < 4; ++i) {
#pragma unroll
    for (int j = 0; j < 4; ++j) {
      float bv = bias[colg0 + j * 16 + lo4];
#pragma unroll
      for (int r = 0; r < 4; ++r) {
        int rowg = row0 + wr * 64 + i * 16 + hi * 4 + r;
        Cp[(size_t)rowg * ldc + cb + j * 16 + lo4] = acc[i][j][r] + bv;
      }
    }
  }
}

// ============================================================
// Complex LayerNorm (fp32 in-place)
// ============================================================
__global__ __launch_bounds__(256) void cln_kernel(
    float* __restrict__ re, float* __restrict__ im,
    const float* __restrict__ gamma, const float* __restrict__ beta)
{
  __shared__ float red[8];
  const int row = blockIdx.x;
  const int tid = threadIdx.x;
  float* pr = re + (size_t)row * DIMM;
  float* pi = im + (size_t)row * DIMM;
  float vr[4], vi[4], mg[4];
  float s = 0.f, s2 = 0.f;
#pragma unroll
  for (int t = 0; t < 4; ++t) {
    int c = tid + t * 256;
    vr[t] = pr[c]; vi[t] = pi[c];
    mg[t] = sqrtf(vr[t] * vr[t] + vi[t] * vi[t]);
    s += mg[t]; s2 += mg[t] * mg[t];
  }
#pragma unroll
  for (int o = 32; o; o >>= 1) { s += __shfl_down(s, o); s2 += __shfl_down(s2, o); }
  if ((tid & 63) == 0) { red[tid >> 6] = s; red[4 + (tid >> 6)] = s2; }
  __syncthreads();
  if (tid == 0) {
    float S = red[0] + red[1] + red[2] + red[3];
    float S2 = red[4] + red[5] + red[6] + red[7];
    float mean = S * (1.f / DIMM);
    float var = S2 * (1.f / DIMM) - mean * mean;
    red[0] = mean;
    red[1] = rsqrtf(var + EPS_LN);
  }
  __syncthreads();
  float mean = red[0], inv = red[1];
#pragma unroll
  for (int t = 0; t < 4; ++t) {
    int c = tid + t * 256;
    float nm = (mg[t] - mean) * inv * gamma[c] + beta[c];
    float invm = mg[t] > 0.f ? 1.f / mg[t] : 0.f;
    float cr = mg[t] > 0.f ? vr[t] * invm : 1.f;
    float ci = mg[t] > 0.f ? vi[t] * invm : 0.f;
    pr[c] = nm * cr;
    pi[c] = nm * ci;
  }
}

// ============================================================
// 1024-pt radix-2 DIF FFT, ortho norm; fp32 in, bf16 out.
// LDS twiddle table (512 roots, 1 sincos/thread) replaces per-butterfly sincos.
// ============================================================
#define FD 4
__global__ __launch_bounds__(512) void fft_kernel(
    const float* __restrict__ inR, const float* __restrict__ inI,
    bf16_t* __restrict__ outR, bf16_t* __restrict__ outI,
    int in_sb, int in_sh, int in_sn, int in_sd,
    int out_sb, int out_sh, int out_sn, int out_sd,
    float sign)
{
  __shared__ float lr[FD][NN + 1], li[FD][NN + 1];
  __shared__ float2 tw[512];
  const int tid = threadIdx.x;
  const int dc = blockIdx.x & 15;
  const int bh = blockIdx.x >> 4;
  const int b = bh >> 4, h = bh & 15;
  const float* bR = inR + (size_t)b * in_sb + (size_t)h * in_sh;
  const float* bI = inI + (size_t)b * in_sb + (size_t)h * in_sh;
  {
    float ang = sign * 3.14159265358979323846f * (float)tid * (1.f / 512.f);
    float sn, cs;
    __sincosf(ang, &sn, &cs);
    tw[tid] = make_float2(cs, sn);
  }
#pragma unroll
  for (int it = 0; it < 8; ++it) {
    int flat = it * 512 + tid;
    int ds = flat & 3, n = flat >> 2;
    size_t ga = (size_t)(dc * FD + ds) * in_sd + (size_t)n * in_sn;
    lr[ds][n] = bR[ga];
    li[ds][n] = bI[ga];
  }
  __syncthreads();
  const int dsub = tid & 3;
  const int jb = tid >> 2;
  for (int hs = 9; hs >= 0; --hs) {
    int half = 1 << hs;
#pragma unroll
    for (int it = 0; it < 4; ++it) {
      int j = jb + it * 128;
      int o = j & (half - 1);
      int i0 = ((j >> hs) << (hs + 1)) + o;
      int i1 = i0 + half;
      float ar = lr[dsub][i0], ai = li[dsub][i0];
      float br_ = lr[dsub][i1], bi_ = li[dsub][i1];
      lr[dsub][i0] = ar + br_;
      li[dsub][i0] = ai + bi_;
      float sr = ar - br_, si = ai - bi_;
      float2 t = tw[o << (9 - hs)];
      lr[dsub][i1] = sr * t.x - si * t.y;
      li[dsub][i1] = sr * t.y + si * t.x;
    }
    __syncthreads();
  }
  bf16_t* oR = outR + (size_t)b * out_sb + (size_t)h * out_sh;
  bf16_t* oI = outI + (size_t)b * out_sb + (size_t)h * out_sh;
#pragma unroll
  for (int it = 0; it < 8; ++it) {
    int flat = it * 512 + tid;
    int ds = flat & 3, n = flat >> 2;
    int rev = __brev((unsigned)n) >> 22;
    size_t ga = (size_t)(dc * FD + ds) * out_sd + (size_t)n * out_sn;
    oR[ga] = (bf16_t)(lr[ds][rev] * 0.03125f);
    oI[ga] = (bf16_t)(li[ds][rev] * 0.03125f);
  }
}

// ============================================================
// Flash attention (unchanged from round 3 — control; rewrite next round
// if it tops the profile). Qf,Kf: [BH,N,128]; VfT: [BH,128,N].
// ============================================================
__global__ __launch_bounds__(256) void fattn(
    const bf16_t* __restrict__ Qf, const bf16_t* __restrict__ Kf,
    const bf16_t* __restrict__ VfT,
    float* __restrict__ Or, float* __restrict__ Oi)
{
  __shared__ bf16_t sK[32][136];
  __shared__ bf16_t sVT[128][40];
  __shared__ bf16_t pbuf[4][16][40];
  const int tid = threadIdx.x;
  const int w = tid >> 6, l = tid & 63;
  const int lo4 = l & 15, hi = l >> 4;
  const int bh = blockIdx.x >> 4;
  const int q0 = (blockIdx.x & 15) * 64;

  bf16x8 aq[4];
  const bf16_t* qp = Qf + (((size_t)bh * NN + q0 + w * 16 + lo4) * 128) + hi * 8;
#pragma unroll
  for (int kk = 0; kk < 4; ++kk) aq[kk] = *(const bf16x8*)(qp + kk * 32);

  f32x4 o[8] = {};
  float m[4] = {-3e38f, -3e38f, -3e38f, -3e38f};
  float ln[4] = {0.f, 0.f, 0.f, 0.f};

  const size_t kbase = (size_t)bh * NN * 128;
  const size_t vbase = (size_t)bh * 128 * NN;

  for (int kv0 = 0; kv0 < NN; kv0 += 32) {
    __syncthreads();
    for (int c = tid; c < 512; c += 256) {
      int r = c >> 4, cc = c & 15;
      *(bf16x8*)&sK[r][cc * 8] =
          *(const bf16x8*)&Kf[kbase + (size_t)(kv0 + r) * 128 + cc * 8];
    }
    for (int c = tid; c < 512; c += 256) {
      int d = c >> 2, kc = c & 3;
      *(bf16x8*)&sVT[d][kc * 8] =
          *(const bf16x8*)&VfT[vbase + (size_t)d * NN + kv0 + kc * 8];
    }
    __syncthreads();

    f32x4 s0 = {}, s1 = {};
#pragma unroll
    for (int kk = 0; kk < 4; ++kk) {
      bf16x8 b0 = *(const bf16x8*)&sK[lo4][kk * 32 + hi * 8];
      bf16x8 b1 = *(const bf16x8*)&sK[16 + lo4][kk * 32 + hi * 8];
      s0 = MFMA16(aq[kk], b0, s0);
      s1 = MFMA16(aq[kk], b1, s1);
    }
    float alpha[4];
#pragma unroll
    for (int r = 0; r < 4; ++r) {
      float a0 = s0[r] * 0.125f, a1 = s1[r] * 0.125f;
      float mx = fmaxf(a0, a1);
      mx = fmaxf(mx, __shfl_xor(mx, 1));
      mx = fmaxf(mx, __shfl_xor(mx, 2));
      mx = fmaxf(mx, __shfl_xor(mx, 4));
      mx = fmaxf(mx, __shfl_xor(mx, 8));
      float mnew = fmaxf(m[r], mx);
      float al = __expf(m[r] - mnew);
      float p0 = __expf(a0 - mnew);
      float p1 = __expf(a1 - mnew);
      s0[r] = p0; s1[r] = p1;
      float rs = p0 + p1;
      rs += __shfl_xor(rs, 1);
      rs += __shfl_xor(rs, 2);
      rs += __shfl_xor(rs, 4);
      rs += __shfl_xor(rs, 8);
      ln[r] = ln[r] * al + rs;
      m[r] = mnew;
      alpha[r] = al;
    }
#pragma unroll
    for (int f = 0; f < 8; ++f) {
      o[f][0] *= alpha[0]; o[f][1] *= alpha[1];
      o[f][2] *= alpha[2]; o[f][3] *= alpha[3];
    }
#pragma unroll
    for (int r = 0; r < 4; ++r) {
      pbuf[w][hi * 4 + r][lo4]      = (bf16_t)s0[r];
      pbuf[w][hi * 4 + r][16 + lo4] = (bf16_t)s1[r];
    }
    bf16x8 pa = *(const bf16x8*)&pbuf[w][lo4][hi * 8];
#pragma unroll
    for (int d0 = 0; d0 < 8; ++d0) {
      bf16x8 bv = *(const bf16x8*)&sVT[d0 * 16 + lo4][hi * 8];
      o[d0] = MFMA16(pa, bv, o[d0]);
    }
  }
#pragma unroll
  for (int r = 0; r < 4; ++r) {
    float inv = 1.f / ln[r];
    int qrow = q0 + w * 16 + hi * 4 + r;
    size_t base = ((size_t)bh * NN + qrow) * 64;
#pragma unroll
    for (int d0 = 0; d0 < 8; ++d0) {
      float val = o[d0][r] * inv;
      int col = d0 * 16 + lo4;
      if (col < 64) Or[base + col] = val;
      else          Oi[base + col - 64] = val;
    }
  }
}

// ============================================================
// Host-side orchestration
// ============================================================
extern "C" void kernel_launch(void* const* d_in, const int* in_sizes, int n_in,
                              void* d_out, int out_size, void* d_ws, size_t ws_size,
                              hipStream_t stream) {
  const float* xr   = (const float*)d_in[0];
  const float* xi   = (const float*)d_in[1];
  const float* Wqr  = (const float*)d_in[2];
  const float* Wqi  = (const float*)d_in[3];
  const float* bqr  = (const float*)d_in[4];
  const float* bqi  = (const float*)d_in[5];
  const float* Wkr  = (const float*)d_in[6];
  const float* Wki  = (const float*)d_in[7];
  const float* bkr  = (const float*)d_in[8];
  const float* bki  = (const float*)d_in[9];
  const float* Wvr  = (const float*)d_in[10];
  const float* Wvi  = (const float*)d_in[11];
  const float* bvr  = (const float*)d_in[12];
  const float* bvi  = (const float*)d_in[13];
  const float* Wor  = (const float*)d_in[14];
  const float* Woi  = (const float*)d_in[15];
  const float* bor  = (const float*)d_in[16];
  const float* boi  = (const float*)d_in[17];
  const float* gq   = (const float*)d_in[18];
  const float* beq  = (const float*)d_in[19];
  const float* gk   = (const float*)d_in[20];
  const float* bek  = (const float*)d_in[21];
  const float* gv   = (const float*)d_in[22];
  const float* bev  = (const float*)d_in[23];

  char* wp = (char*)d_ws;
  bf16_t* Axaug = (bf16_t*)wp;  wp += (size_t)4096 * 2048 * 2;
  bf16_t* Wcat  = (bf16_t*)wp;  wp += (size_t)2048 * 2048 * 2;
  float*  bcat  = (float*)wp;   wp += (size_t)2048 * 4;
  float*  Ar    = (float*)wp;   wp += (size_t)4096 * 1024 * 4;
  float*  Ai    = (float*)wp;   wp += (size_t)4096 * 1024 * 4;
  bf16_t* Qf    = (bf16_t*)wp;  wp += (size_t)64 * 1024 * 128 * 2;
  bf16_t* Kf    = (bf16_t*)wp;  wp += (size_t)64 * 1024 * 128 * 2;
  bf16_t* VfT   = (bf16_t*)wp;  wp += (size_t)64 * 1024 * 128 * 2;
  bf16_t* Yaug  = Qf;

  const dim3 gGemm(16, 32);
  const int gPackX = (4096 * 2048 / 8) / 256;
  const int gPackW = (2048 * 2048 / 8) / 256;
  const int gCln = BN;
  const int gFft = 64 * 16;
  const int gAtt = 64 * 16;

  pack_x<<<gPackX, 256, 0, stream>>>(xr, xi, Axaug);

  // ---- Q ----
  pack_w<<<gPackW, 256, 0, stream>>>(Wqr, Wqi, bqr, bqi, Wcat, bcat);
  gemm_bf16<<<gGemm, 256, 0, stream>>>(Axaug, Wcat, bcat, Ar, Ai, 1024);
  cln_kernel<<<gCln, 256, 0, stream>>>(Ar, Ai, gq, beq);
  fft_kernel<<<gFft, 512, 0, stream>>>(Ar, Ai, Qf, Qf + 64,
      NN * DIMM, DHH, DIMM, 1,
      16 * NN * 128, NN * 128, 128, 1, -1.0f);
  // ---- K ----
  pack_w<<<gPackW, 256, 0, stream>>>(Wkr, Wki, bkr, bki, Wcat, bcat);
  gemm_bf16<<<gGemm, 256, 0, stream>>>(Axaug, Wcat, bcat, Ar, Ai, 1024);
  cln_kernel<<<gCln, 256, 0, stream>>>(Ar, Ai, gk, bek);
  fft_kernel<<<gFft, 512, 0, stream>>>(Ar, Ai, Kf, Kf + 64,
      NN * DIMM, DHH, DIMM, 1,
      16 * NN * 128, NN * 128, 128, 1, -1.0f);
  // ---- V (transposed output [BH,128,N]) ----
  pack_w<<<gPackW, 256, 0, stream>>>(Wvr, Wvi, bvr, bvi, Wcat, bcat);
  gemm_bf16<<<gGemm, 256, 0, stream>>>(Axaug, Wcat, bcat, Ar, Ai, 1024);
  cln_kernel<<<gCln, 256, 0, stream>>>(Ar, Ai, gv, bev);
  fft_kernel<<<gFft, 512, 0, stream>>>(Ar, Ai, VfT, VfT + (size_t)64 * NN,
      NN * DIMM, DHH, DIMM, 1,
      16 * 128 * NN, 128 * NN, 1, NN, -1.0f);
  // ---- flash attention -> Or/Oi in Ar/Ai ----
  fattn<<<gAtt, 256, 0, stream>>>(Qf, Kf, VfT, Ar, Ai);
  // ---- inverse FFT -> Yaug bf16 [4096][2048] ----
  fft_kernel<<<gFft, 512, 0, stream>>>(Ar, Ai, Yaug, Yaug + 1024,
      16 * NN * 64, NN * 64, 64, 1,
      NN * 2048, 64, 2048, 1, +1.0f);
  // ---- output projection straight into d_out ----
  float* yout = (float*)d_out;
  pack_w<<<gPackW, 256, 0, stream>>>(Wor, Woi, bor, boi, Wcat, bcat);
  gemm_bf16<<<gGemm, 256, 0, stream>>>(Yaug, Wcat, bcat, yout, yout + 1024, 2048);
}

// Round 5
// 640.055 us; speedup vs baseline: 7.0110x; 1.0383x over previous
//
#include <hip/hip_runtime.h>
#include <math.h>

#define BB 4
#define NN 1024
#define DIMM 1024
#define HHH 16
#define DHH 64
#define BN 4096            // B*N rows
#define EPS_LN 1e-6f

typedef __bf16 bf16_t;
typedef __bf16 bf16x8 __attribute__((ext_vector_type(8)));
typedef float f32x4 __attribute__((ext_vector_type(4)));
typedef float f32x16 __attribute__((ext_vector_type(16)));
#define MFMA16(a, b, c) __builtin_amdgcn_mfma_f32_16x16x32_bf16(a, b, c, 0, 0, 0)
#define MFMA32(a, b, c) __builtin_amdgcn_mfma_f32_32x32x16_bf16(a, b, c, 0, 0, 0)
#define AS1 __attribute__((address_space(1)))
#define AS3 __attribute__((address_space(3)))

__device__ inline unsigned pk2(float a, float b) {
  union { bf16_t h[2]; unsigned u; } c;
  c.h[0] = (bf16_t)a; c.h[1] = (bf16_t)b;
  return c.u;
}

// ============================================================
// pack_x: Axaug[4096][2048] = bf16([xr | xi])
// ============================================================
__global__ __launch_bounds__(256) void pack_x(
    const float* __restrict__ xr, const float* __restrict__ xi,
    bf16_t* __restrict__ out)
{
  int t = blockIdx.x * 256 + threadIdx.x;
  size_t e = (size_t)t * 8;
  int row = (int)(e >> 11), col = (int)(e & 2047);
  const float* src = (col < 1024) ? (xr + (size_t)row * 1024 + col)
                                  : (xi + (size_t)row * 1024 + col - 1024);
  float4 a = *(const float4*)src;
  float4 b = *(const float4*)(src + 4);
  bf16x8 o;
  o[0] = (bf16_t)a.x; o[1] = (bf16_t)a.y; o[2] = (bf16_t)a.z; o[3] = (bf16_t)a.w;
  o[4] = (bf16_t)b.x; o[5] = (bf16_t)b.y; o[6] = (bf16_t)b.z; o[7] = (bf16_t)b.w;
  *(bf16x8*)(out + e) = o;
}

// ============================================================
// pack_w: Wcat[2048][2048]: rows 0-1023 = [Wr | -Wi], rows 1024-2047 = [Wi | Wr]
// ============================================================
__global__ __launch_bounds__(256) void pack_w(
    const float* __restrict__ Wr, const float* __restrict__ Wi,
    const float* __restrict__ br, const float* __restrict__ bi,
    bf16_t* __restrict__ Wcat, float* __restrict__ bcat)
{
  int t = blockIdx.x * 256 + threadIdx.x;
  size_t e = (size_t)t * 8;
  int row = (int)(e >> 11), col = (int)(e & 2047);
  const float* src;
  float sgn = 1.f;
  if (row < 1024) {
    if (col < 1024) src = Wr + (size_t)row * 1024 + col;
    else          { src = Wi + (size_t)row * 1024 + col - 1024; sgn = -1.f; }
  } else {
    int r2 = row - 1024;
    if (col < 1024) src = Wi + (size_t)r2 * 1024 + col;
    else            src = Wr + (size_t)r2 * 1024 + col - 1024;
  }
  float4 a = *(const float4*)src;
  float4 b = *(const float4*)(src + 4);
  bf16x8 o;
  o[0] = (bf16_t)(sgn * a.x); o[1] = (bf16_t)(sgn * a.y);
  o[2] = (bf16_t)(sgn * a.z); o[3] = (bf16_t)(sgn * a.w);
  o[4] = (bf16_t)(sgn * b.x); o[5] = (bf16_t)(sgn * b.y);
  o[6] = (bf16_t)(sgn * b.z); o[7] = (bf16_t)(sgn * b.w);
  *(bf16x8*)(Wcat + e) = o;
  if (e < 2048) {
#pragma unroll
    for (int j = 0; j < 8; ++j) {
      int n = (int)e + j;
      bcat[n] = (n < 1024) ? br[n] : bi[n - 1024];
    }
  }
}

// ============================================================
// bf16 MFMA GEMM (NT), m97 structure (unchanged from round 4).
// ============================================================
__global__ __launch_bounds__(256) void gemm_bf16(
    const bf16_t* __restrict__ A, const bf16_t* __restrict__ Bt,
    const float* __restrict__ bias,
    float* __restrict__ Cr, float* __restrict__ Ci, int ldc)
{
  __shared__ bf16_t sA[128 * 64];
  __shared__ bf16_t sB[128 * 64];
  const int tid = threadIdx.x;
  const int w = tid >> 6, l = tid & 63;
  const int lo4 = l & 15, hi = l >> 4;
  const int wr = w >> 1, wc = w & 1;
  const int row0 = blockIdx.y * 128, col0 = blockIdx.x * 128;

  const int srow = (l >> 3);
  const int scol = (l & 7) * 8;
  const bf16_t* gA[4];
  const bf16_t* gB[4];
#pragma unroll
  for (int i = 0; i < 4; ++i) {
    int r = (w * 4 + i) * 8 + srow;
    gA[i] = A  + (size_t)(row0 + r) * 2048 + scol;
    gB[i] = Bt + (size_t)(col0 + r) * 2048 + scol;
  }

  f32x4 acc[4][4] = {};
  for (int k0 = 0; k0 < 2048; k0 += 64) {
    __syncthreads();
#pragma unroll
    for (int i = 0; i < 4; ++i) {
      __builtin_amdgcn_global_load_lds((const AS1 void*)(gA[i] + k0),
                                       (AS3 void*)&sA[(w * 4 + i) * 512], 16, 0, 0);
      __builtin_amdgcn_global_load_lds((const AS1 void*)(gB[i] + k0),
                                       (AS3 void*)&sB[(w * 4 + i) * 512], 16, 0, 0);
    }
    __syncthreads();
#pragma unroll
    for (int kk = 0; kk < 2; ++kk) {
      bf16x8 am[4], bn[4];
#pragma unroll
      for (int i = 0; i < 4; ++i)
        am[i] = *(const bf16x8*)&sA[(wr * 64 + i * 16 + lo4) * 64 + kk * 32 + hi * 8];
#pragma unroll
      for (int j = 0; j < 4; ++j)
        bn[j] = *(const bf16x8*)&sB[(wc * 64 + j * 16 + lo4) * 64 + kk * 32 + hi * 8];
#pragma unroll
      for (int i = 0; i < 4; ++i)
#pragma unroll
        for (int j = 0; j < 4; ++j)
          acc[i][j] = MFMA16(am[i], bn[j], acc[i][j]);
    }
  }
  const int colg0 = col0 + wc * 64;
  float* Cp = (colg0 < 1024) ? Cr : Ci;
  const int cb = colg0 & 1023;
#pragma unroll
  for (int i = 0; i < 4; ++i) {
#pragma unroll
    for (int j = 0; j < 4; ++j) {
      float bv = bias[colg0 + j * 16 + lo4];
#pragma unroll
      for (int r = 0; r < 4; ++r) {
        int rowg = row0 + wr * 64 + i * 16 + hi * 4 + r;
        Cp[(size_t)rowg * ldc + cb + j * 16 + lo4] = acc[i][j][r] + bv;
      }
    }
  }
}

// ============================================================
// Complex LayerNorm (fp32 in-place, unchanged)
// ============================================================
__global__ __launch_bounds__(256) void cln_kernel(
    float* __restrict__ re, float* __restrict__ im,
    const float* __restrict__ gamma, const float* __restrict__ beta)
{
  __shared__ float red[8];
  const int row = blockIdx.x;
  const int tid = threadIdx.x;
  float* pr = re + (size_t)row * DIMM;
  float* pi = im + (size_t)row * DIMM;
  float vr[4], vi[4], mg[4];
  float s = 0.f, s2 = 0.f;
#pragma unroll
  for (int t = 0; t < 4; ++t) {
    int c = tid + t * 256;
    vr[t] = pr[c]; vi[t] = pi[c];
    mg[t] = sqrtf(vr[t] * vr[t] + vi[t] * vi[t]);
    s += mg[t]; s2 += mg[t] * mg[t];
  }
#pragma unroll
  for (int o = 32; o; o >>= 1) { s += __shfl_down(s, o); s2 += __shfl_down(s2, o); }
  if ((tid & 63) == 0) { red[tid >> 6] = s; red[4 + (tid >> 6)] = s2; }
  __syncthreads();
  if (tid == 0) {
    float S = red[0] + red[1] + red[2] + red[3];
    float S2 = red[4] + red[5] + red[6] + red[7];
    float mean = S * (1.f / DIMM);
    float var = S2 * (1.f / DIMM) - mean * mean;
    red[0] = mean;
    red[1] = rsqrtf(var + EPS_LN);
  }
  __syncthreads();
  float mean = red[0], inv = red[1];
#pragma unroll
  for (int t = 0; t < 4; ++t) {
    int c = tid + t * 256;
    float nm = (mg[t] - mean) * inv * gamma[c] + beta[c];
    float invm = mg[t] > 0.f ? 1.f / mg[t] : 0.f;
    float cr = mg[t] > 0.f ? vr[t] * invm : 1.f;
    float ci = mg[t] > 0.f ? vi[t] * invm : 0.f;
    pr[c] = nm * cr;
    pi[c] = nm * ci;
  }
}

// ============================================================
// 1024-pt radix-2 DIF FFT, LDS twiddle table; fp32 in, bf16 out.
// oscale: ortho 1/32, optionally with extra factors folded in.
// ============================================================
#define FD 4
__global__ __launch_bounds__(512) void fft_kernel(
    const float* __restrict__ inR, const float* __restrict__ inI,
    bf16_t* __restrict__ outR, bf16_t* __restrict__ outI,
    int in_sb, int in_sh, int in_sn, int in_sd,
    int out_sb, int out_sh, int out_sn, int out_sd,
    float sign, float oscale)
{
  __shared__ float lr[FD][NN + 1], li[FD][NN + 1];
  __shared__ float2 tw[512];
  const int tid = threadIdx.x;
  const int dc = blockIdx.x & 15;
  const int bh = blockIdx.x >> 4;
  const int b = bh >> 4, h = bh & 15;
  const float* bR = inR + (size_t)b * in_sb + (size_t)h * in_sh;
  const float* bI = inI + (size_t)b * in_sb + (size_t)h * in_sh;
  {
    float ang = sign * 3.14159265358979323846f * (float)tid * (1.f / 512.f);
    float sn, cs;
    __sincosf(ang, &sn, &cs);
    tw[tid] = make_float2(cs, sn);
  }
#pragma unroll
  for (int it = 0; it < 8; ++it) {
    int flat = it * 512 + tid;
    int ds = flat & 3, n = flat >> 2;
    size_t ga = (size_t)(dc * FD + ds) * in_sd + (size_t)n * in_sn;
    lr[ds][n] = bR[ga];
    li[ds][n] = bI[ga];
  }
  __syncthreads();
  const int dsub = tid & 3;
  const int jb = tid >> 2;
  for (int hs = 9; hs >= 0; --hs) {
    int half = 1 << hs;
#pragma unroll
    for (int it = 0; it < 4; ++it) {
      int j = jb + it * 128;
      int o = j & (half - 1);
      int i0 = ((j >> hs) << (hs + 1)) + o;
      int i1 = i0 + half;
      float ar = lr[dsub][i0], ai = li[dsub][i0];
      float br_ = lr[dsub][i1], bi_ = li[dsub][i1];
      lr[dsub][i0] = ar + br_;
      li[dsub][i0] = ai + bi_;
      float sr = ar - br_, si = ai - bi_;
      float2 t = tw[o << (9 - hs)];
      lr[dsub][i1] = sr * t.x - si * t.y;
      li[dsub][i1] = sr * t.y + si * t.x;
    }
    __syncthreads();
  }
  bf16_t* oR = outR + (size_t)b * out_sb + (size_t)h * out_sh;
  bf16_t* oI = outI + (size_t)b * out_sb + (size_t)h * out_sh;
#pragma unroll
  for (int it = 0; it < 8; ++it) {
    int flat = it * 512 + tid;
    int ds = flat & 3, n = flat >> 2;
    int rev = __brev((unsigned)n) >> 22;
    size_t ga = (size_t)(dc * FD + ds) * out_sd + (size_t)n * out_sn;
    oR[ga] = (bf16_t)(lr[ds][rev] * oscale);
    oI[ga] = (bf16_t)(li[ds][rev] * oscale);
  }
}

// ============================================================
// Flash attention, swapped-operand 32x32 MFMA, NO LDS.
// S^T = mfma(K, Q): lane holds 16 k-scores for q = lane&31.
// Softmax in-register (15 fmax + 1 shfl_xor(32)); P->B-frag via 8
// packed-u32 shfl_xor(32) + cndmask. O^T accumulated per 32-d block,
// stored coalesced to OT [BH,128,N] (iFFT consumes via strides).
// Scale 1/8 is pre-folded into Qf (FFT output scale).
// Grid: 64 bh x 8 qblocks; block = 4 waves x 32 q-rows.
// ============================================================
__global__ __launch_bounds__(256) void fattn(
    const bf16_t* __restrict__ Qf, const bf16_t* __restrict__ Kf,
    const bf16_t* __restrict__ VfT, float* __restrict__ OT)
{
  const int tid = threadIdx.x;
  const int w = tid >> 6, l = tid & 63;
  const int lq = l & 31;            // q-column within wave tile
  const int h = l >> 5;             // lane half
  const int bh = blockIdx.x >> 3;
  const int q0 = (blockIdx.x & 7) * 128 + w * 32;

  // Q fragments (B-operand): frag kk holds k = kk*16 + h*8 + j
  bf16x8 bq[8];
  const bf16_t* qp = Qf + ((size_t)bh * NN + q0 + lq) * 128 + h * 8;
#pragma unroll
  for (int kk = 0; kk < 8; ++kk) bq[kk] = *(const bf16x8*)(qp + kk * 16);

  f32x16 o[4] = {};                 // O^T d-blocks (compile-time indexed only)
  float m = -3e38f, ln = 0.f;

  const bf16_t* kb = Kf + (size_t)bh * NN * 128 + h * 8;
  const bf16_t* vb = VfT + (size_t)bh * 128 * NN;

  for (int kv0 = 0; kv0 < NN; kv0 += 32) {
    // ---- S^T[k][q] over d=128 ----
    f32x16 s = {};
    const bf16_t* kpt = kb + (size_t)(kv0 + lq) * 128;
#pragma unroll
    for (int kk = 0; kk < 8; ++kk) {
      bf16x8 ak = *(const bf16x8*)(kpt + kk * 16);
      s = MFMA32(ak, bq[kk], s);
    }
    // ---- online softmax (lane owns 16 k-rows of its q-column) ----
    float pmax = s[0];
#pragma unroll
    for (int r = 1; r < 16; ++r) pmax = fmaxf(pmax, s[r]);
    pmax = fmaxf(pmax, __shfl_xor(pmax, 32));
    float mnew = fmaxf(m, pmax);
    float alpha = __expf(m - mnew);
    float pf[16];
    float rs = 0.f;
#pragma unroll
    for (int r = 0; r < 16; ++r) { pf[r] = __expf(s[r] - mnew); rs += pf[r]; }
    rs += __shfl_xor(rs, 32);
    ln = ln * alpha + rs;
    m = mnew;
#pragma unroll
    for (int db = 0; db < 4; ++db)
#pragma unroll
      for (int r = 0; r < 16; ++r) o[db][r] *= alpha;
    // ---- P -> bf16 B-fragments via cross-half exchange ----
    // own reg r covers k_row = (r&3) + 8*(r>>2) + 4*h
    unsigned pw[8], qw[8];
#pragma unroll
    for (int i = 0; i < 8; ++i) pw[i] = pk2(pf[2 * i], pf[2 * i + 1]);
#pragma unroll
    for (int i = 0; i < 8; ++i) qw[i] = (unsigned)__shfl_xor((int)pw[i], 32);
#pragma unroll
    for (int ks = 0; ks < 2; ++ks) {
      union { unsigned u[4]; bf16x8 v; } bp;
      bp.u[0] = h ? qw[4 * ks + 2] : pw[4 * ks + 0];
      bp.u[1] = h ? qw[4 * ks + 3] : pw[4 * ks + 1];
      bp.u[2] = h ? pw[4 * ks + 2] : qw[4 * ks + 0];
      bp.u[3] = h ? pw[4 * ks + 3] : qw[4 * ks + 1];
      // ---- O^T[db] += V^T . P ----
#pragma unroll
      for (int db = 0; db < 4; ++db) {
        const bf16_t* va = vb + (size_t)(db * 32 + lq) * NN + kv0 + ks * 16 + h * 8;
        bf16x8 av = *(const bf16x8*)va;
        o[db] = MFMA32(av, bp.v, o[db]);
      }
    }
  }
  // ---- normalize + coalesced O^T store ----
  float inv = 1.f / ln;
  const size_t otb = (size_t)bh * 128 * NN + q0 + lq;
#pragma unroll
  for (int db = 0; db < 4; ++db)
#pragma unroll
    for (int r = 0; r < 16; ++r) {
      int dl = (r & 3) + 8 * (r >> 2) + 4 * h;
      OT[otb + (size_t)(db * 32 + dl) * NN] = o[db][r] * inv;
    }
}

// ============================================================
// Host-side orchestration
// ============================================================
extern "C" void kernel_launch(void* const* d_in, const int* in_sizes, int n_in,
                              void* d_out, int out_size, void* d_ws, size_t ws_size,
                              hipStream_t stream) {
  const float* xr   = (const float*)d_in[0];
  const float* xi   = (const float*)d_in[1];
  const float* Wqr  = (const float*)d_in[2];
  const float* Wqi  = (const float*)d_in[3];
  const float* bqr  = (const float*)d_in[4];
  const float* bqi  = (const float*)d_in[5];
  const float* Wkr  = (const float*)d_in[6];
  const float* Wki  = (const float*)d_in[7];
  const float* bkr  = (const float*)d_in[8];
  const float* bki  = (const float*)d_in[9];
  const float* Wvr  = (const float*)d_in[10];
  const float* Wvi  = (const float*)d_in[11];
  const float* bvr  = (const float*)d_in[12];
  const float* bvi  = (const float*)d_in[13];
  const float* Wor  = (const float*)d_in[14];
  const float* Woi  = (const float*)d_in[15];
  const float* bor  = (const float*)d_in[16];
  const float* boi  = (const float*)d_in[17];
  const float* gq   = (const float*)d_in[18];
  const float* beq  = (const float*)d_in[19];
  const float* gk   = (const float*)d_in[20];
  const float* bek  = (const float*)d_in[21];
  const float* gv   = (const float*)d_in[22];
  const float* bev  = (const float*)d_in[23];

  char* wp = (char*)d_ws;
  bf16_t* Axaug = (bf16_t*)wp;  wp += (size_t)4096 * 2048 * 2;
  bf16_t* Wcat  = (bf16_t*)wp;  wp += (size_t)2048 * 2048 * 2;
  float*  bcat  = (float*)wp;   wp += (size_t)2048 * 4;
  float*  Ar    = (float*)wp;   wp += (size_t)4096 * 1024 * 4;
  float*  Ai    = (float*)wp;   wp += (size_t)4096 * 1024 * 4;
  bf16_t* Qf    = (bf16_t*)wp;  wp += (size_t)64 * 1024 * 128 * 2;
  bf16_t* Kf    = (bf16_t*)wp;  wp += (size_t)64 * 1024 * 128 * 2;
  bf16_t* VfT   = (bf16_t*)wp;  wp += (size_t)64 * 1024 * 128 * 2;
  bf16_t* Yaug  = Qf;
  float*  OT    = Ar;   // attn output O^T [BH,128,N] fp32 (spans Ar+Ai)

  const dim3 gGemm(16, 32);
  const int gPackX = (4096 * 2048 / 8) / 256;
  const int gPackW = (2048 * 2048 / 8) / 256;
  const int gCln = BN;
  const int gFft = 64 * 16;
  const int gAtt = 64 * 8;

  pack_x<<<gPackX, 256, 0, stream>>>(xr, xi, Axaug);

  // ---- Q (FFT output scale folds in the 1/8 attention scale) ----
  pack_w<<<gPackW, 256, 0, stream>>>(Wqr, Wqi, bqr, bqi, Wcat, bcat);
  gemm_bf16<<<gGemm, 256, 0, stream>>>(Axaug, Wcat, bcat, Ar, Ai, 1024);
  cln_kernel<<<gCln, 256, 0, stream>>>(Ar, Ai, gq, beq);
  fft_kernel<<<gFft, 512, 0, stream>>>(Ar, Ai, Qf, Qf + 64,
      NN * DIMM, DHH, DIMM, 1,
      16 * NN * 128, NN * 128, 128, 1, -1.0f, 0.03125f * 0.125f);
  // ---- K ----
  pack_w<<<gPackW, 256, 0, stream>>>(Wkr, Wki, bkr, bki, Wcat, bcat);
  gemm_bf16<<<gGemm, 256, 0, stream>>>(Axaug, Wcat, bcat, Ar, Ai, 1024);
  cln_kernel<<<gCln, 256, 0, stream>>>(Ar, Ai, gk, bek);
  fft_kernel<<<gFft, 512, 0, stream>>>(Ar, Ai, Kf, Kf + 64,
      NN * DIMM, DHH, DIMM, 1,
      16 * NN * 128, NN * 128, 128, 1, -1.0f, 0.03125f);
  // ---- V (transposed output [BH,128,N]) ----
  pack_w<<<gPackW, 256, 0, stream>>>(Wvr, Wvi, bvr, bvi, Wcat, bcat);
  gemm_bf16<<<gGemm, 256, 0, stream>>>(Axaug, Wcat, bcat, Ar, Ai, 1024);
  cln_kernel<<<gCln, 256, 0, stream>>>(Ar, Ai, gv, bev);
  fft_kernel<<<gFft, 512, 0, stream>>>(Ar, Ai, VfT, VfT + (size_t)64 * NN,
      NN * DIMM, DHH, DIMM, 1,
      16 * 128 * NN, 128 * NN, 1, NN, -1.0f, 0.03125f);
  // ---- flash attention -> OT [BH,128,N] fp32 ----
  fattn<<<gAtt, 256, 0, stream>>>(Qf, Kf, VfT, OT);
  // ---- inverse FFT: OT (d-major) -> Yaug bf16 [4096][2048] ----
  fft_kernel<<<gFft, 512, 0, stream>>>(OT, OT + (size_t)64 * NN, Yaug, Yaug + 1024,
      16 * 128 * NN, 128 * NN, 1, NN,
      NN * 2048, 64, 2048, 1, +1.0f, 0.03125f);
  // ---- output projection straight into d_out ----
  float* yout = (float*)d_out;
  pack_w<<<gPackW, 256, 0, stream>>>(Wor, Woi, bor, boi, Wcat, bcat);
  gemm_bf16<<<gGemm, 256, 0, stream>>>(Yaug, Wcat, bcat, yout, yout + 1024, 2048);
}